// Round 2
// baseline (3809.280 us; speedup 1.0000x reference)
//
#include <hip/hip_runtime.h>
#include <hip/hip_bf16.h>
#include <float.h>

// Problem constants (fixed by the reference)
constexpr int NENT  = 100000;
constexpr int DDIM  = 256;
constexpr int BQ    = 64;
constexpr int CANDN = 10000;
constexpr int KTOP  = 10;

// ---------------------------------------------------------------------------
// K1: targets (stored transposed [d][b]) + query hash codes (packed 4x u32)
// ---------------------------------------------------------------------------
__global__ __launch_bounds__(128) void k_targets(
    const int* __restrict__ head, const int* __restrict__ rel,
    const float* __restrict__ E, const float* __restrict__ Rm,
    const float* __restrict__ proj,
    float* __restrict__ tgtT, unsigned* __restrict__ thash)
{
    __shared__ float tg[DDIM];
    int b = blockIdx.x;
    int tid = threadIdx.x;
    int h = head[b], r = rel[b];
    for (int d = tid; d < DDIM; d += 128) {
        float v = E[h*DDIM + d] * Rm[r*DDIM + d];
        tg[d] = v;
        tgtT[d*BQ + b] = v;   // transposed for coalesced W-staging in K2
    }
    __syncthreads();
    int t = tid >> 5, hh = tid & 31;
    float acc = 0.f;
    #pragma unroll 8
    for (int d = 0; d < DDIM; d++)
        acc += tg[d] * proj[(t*DDIM + d)*32 + hh];
    unsigned long long m = __ballot(acc > 0.0f);
    int lane = tid & 63, w = tid >> 6;
    if (lane == 0) {
        // wave0 -> words t=0,1 ; wave1 -> words t=2,3 ; bit position = h
        thash[b*4 + w*2 + 0] = (unsigned)(m & 0xffffffffull);
        thash[b*4 + w*2 + 1] = (unsigned)(m >> 32);
    }
}

// ---------------------------------------------------------------------------
// K2: fused GEMM  out[n][c] = sum_d E[n][d] * W[d][c]
//     cols 0..127  -> hash bits (proj), packed into ahash[n][4]
//     cols 128..191 -> DistMult scores vs the 64 query targets -> scores[b][n]
// ---------------------------------------------------------------------------
constexpr int TILE_E = 128;
constexpr int KB = 32;
constexpr int COLS = 192;
constexpr int K2_THREADS = 384;
constexpr int ETS = 132;   // Et row stride (padded, 16B-aligned)

__global__ __launch_bounds__(K2_THREADS) void k_gemm(
    const float* __restrict__ E, const float* __restrict__ proj,
    const float* __restrict__ tgtT,
    unsigned* __restrict__ ahash, float* __restrict__ scores)
{
    __shared__ __align__(16) float Wt[KB*COLS];      // [dd][col]   24576 B
    __shared__ __align__(16) float Et[KB*ETS];       // [dd][e]     16896 B
    __shared__ __align__(16) unsigned bitsW[TILE_E*4]; //            2048 B

    int tid = threadIdx.x;
    int cg = tid % 48;           // 4 cols: c0 = 4*cg
    int eg = tid / 48;           // 16 entities: e = 16*eg .. +15
    int n0 = blockIdx.x * TILE_E;

    float acc[16][4];
    #pragma unroll
    for (int i = 0; i < 16; i++) {
        acc[i][0] = 0.f; acc[i][1] = 0.f; acc[i][2] = 0.f; acc[i][3] = 0.f;
    }

    for (int ch = 0; ch < DDIM/KB; ch++) {
        int d0 = ch * KB;
        __syncthreads();
        // ---- stage W chunk: 32 x 192 floats ----
        #pragma unroll
        for (int s = 0; s < 4; s++) {
            int f  = tid + s*K2_THREADS;       // < 1536 float4s
            int dr = f / 48;
            int cp = (f % 48) * 4;
            float4 v;
            if (cp < 128) {
                int t = cp >> 5;
                v = *(const float4*)(proj + (t*DDIM + d0 + dr)*32 + (cp & 31));
            } else {
                v = *(const float4*)(tgtT + (d0 + dr)*BQ + (cp - 128));
            }
            *(float4*)&Wt[dr*COLS + cp] = v;
        }
        // ---- stage E chunk transposed: Et[dd][row] ----
        #pragma unroll
        for (int s = 0; s < 3; s++) {
            int f = tid + s*K2_THREADS;
            if (f < 1024) {
                int row = f >> 3;
                int cj  = (f & 7) * 4;
                int n = n0 + row; if (n >= NENT) n = NENT - 1;  // clamp (unused rows)
                float4 v = *(const float4*)(E + n*DDIM + d0 + cj);
                Et[(cj+0)*ETS + row] = v.x;
                Et[(cj+1)*ETS + row] = v.y;
                Et[(cj+2)*ETS + row] = v.z;
                Et[(cj+3)*ETS + row] = v.w;
            }
        }
        __syncthreads();
        // ---- compute: 32 d-steps, 64 FMA per step per thread ----
        #pragma unroll 4
        for (int dd = 0; dd < KB; dd++) {
            float4 w = *(const float4*)&Wt[dd*COLS + cg*4];
            const float* ep = &Et[dd*ETS + eg*16];
            float4 e0 = *(const float4*)(ep + 0);
            float4 e1 = *(const float4*)(ep + 4);
            float4 e2 = *(const float4*)(ep + 8);
            float4 e3 = *(const float4*)(ep + 12);
            float ev[16] = {e0.x,e0.y,e0.z,e0.w, e1.x,e1.y,e1.z,e1.w,
                            e2.x,e2.y,e2.z,e2.w, e3.x,e3.y,e3.z,e3.w};
            #pragma unroll
            for (int i = 0; i < 16; i++) {
                acc[i][0] += ev[i] * w.x;
                acc[i][1] += ev[i] * w.y;
                acc[i][2] += ev[i] * w.z;
                acc[i][3] += ev[i] * w.w;
            }
        }
    }

    // ---- emit ----
    __syncthreads();
    for (int i = tid; i < TILE_E*4; i += K2_THREADS) bitsW[i] = 0u;
    __syncthreads();
    if (cg < 32) {
        // hash cols: c0 = 4*cg in [0,128)
        int t  = (cg*4) >> 5;
        int sh = (cg*4) & 31;
        #pragma unroll
        for (int i = 0; i < 16; i++) {
            unsigned m = (acc[i][0] > 0.f ? 1u : 0u) | (acc[i][1] > 0.f ? 2u : 0u)
                       | (acc[i][2] > 0.f ? 4u : 0u) | (acc[i][3] > 0.f ? 8u : 0u);
            atomicOr(&bitsW[(eg*16 + i)*4 + t], m << sh);
        }
    } else {
        // score cols: b = 4*cg - 128 .. +3
        int b0 = cg*4 - 128;
        #pragma unroll
        for (int c = 0; c < 4; c++) {
            int b = b0 + c;
            #pragma unroll
            for (int j = 0; j < 4; j++) {
                int n = n0 + eg*16 + j*4;
                if (n < NENT) {
                    float4 v = make_float4(acc[j*4+0][c], acc[j*4+1][c],
                                           acc[j*4+2][c], acc[j*4+3][c]);
                    *(float4*)(scores + (size_t)b*NENT + n) = v;
                }
            }
        }
    }
    __syncthreads();
    if (tid < TILE_E) {
        int n = n0 + tid;
        if (n < NENT) {
            uint4 v = *(uint4*)&bitsW[tid*4];
            *(uint4*)(ahash + n*4) = v;
        }
    }
}

// ---------------------------------------------------------------------------
// K3 (NEW): per-query dist bytes + histogram -> d*, quota R; then a single
// wave finds nCut = index of the R-th entity (index order) with dist == d*.
// Candidacy becomes the pure predicate: d < d*  ||  (d == d* && n <= nCut).
// ---------------------------------------------------------------------------
__global__ __launch_bounds__(256) void k_prep(
    const unsigned* __restrict__ ahash, const unsigned* __restrict__ thash,
    unsigned char* __restrict__ dist8, int* __restrict__ dsG, int* __restrict__ ncG)
{
    __shared__ unsigned hist[129];
    __shared__ int dsS, rS;
    int b = blockIdx.x, tid = threadIdx.x;
    for (int i = tid; i < 129; i += 256) hist[i] = 0u;
    __syncthreads();
    uint4 tw = *(const uint4*)(thash + b*4);
    unsigned char* drow = dist8 + (size_t)b * NENT;
    for (int n = tid; n < NENT; n += 256) {
        uint4 a = *(const uint4*)(ahash + (size_t)n*4);
        int d = __popc(a.x^tw.x) + __popc(a.y^tw.y) +
                __popc(a.z^tw.z) + __popc(a.w^tw.w);
        drow[n] = (unsigned char)d;
        atomicAdd(&hist[d], 1u);
    }
    __syncthreads();
    if (tid == 0) {
        unsigned cum = 0;
        for (int d = 0; d < 129; d++) {
            unsigned c = cum + hist[d];
            if (c >= (unsigned)CANDN) {
                dsS = d; rS = (int)(CANDN - cum); dsG[b] = d;
                break;
            }
            cum = c;
        }
    }
    __syncthreads();
    if (tid < 64) {   // wave 0 only: find nCut (uniform loop, ballot scan)
        int ds = dsS;
        unsigned R = (unsigned)rS;   // 1 <= R <= hist[ds]
        unsigned cnt = 0;
        for (int base = 0; base < NENT; base += 64) {
            int n = base + tid;
            bool eq = (n < NENT) && (drow[n] == (unsigned char)ds);
            unsigned long long m = __ballot(eq);
            unsigned c = __popcll(m);
            if (cnt + c >= R) {
                unsigned pre = __popcll(m & ((1ull << tid) - 1ull));
                if (eq && (cnt + pre + 1u == R)) ncG[b] = n;
                break;
            }
            cnt += c;
        }
    }
}

// ---------------------------------------------------------------------------
// K4 (NEW): brute-force exact top-10: 10 rounds of block-wide argmax over all
// entities passing the candidacy predicate, excluding already-chosen indices.
// Stateless across entities => trivially matches reference semantics.
// ---------------------------------------------------------------------------
__global__ __launch_bounds__(256) void k_top(
    const unsigned char* __restrict__ dist8, const float* __restrict__ scores,
    const int* __restrict__ dsG, const int* __restrict__ ncG,
    float* __restrict__ out)
{
    __shared__ float rs[256];
    __shared__ int   rn[256];
    __shared__ int   chosen[KTOP];
    int b = blockIdx.x, tid = threadIdx.x;
    int ds = dsG[b], nc = ncG[b];
    const unsigned char* drow = dist8 + (size_t)b*NENT;
    const float* srow = scores + (size_t)b*NENT;

    for (int r = 0; r < KTOP; r++) {
        float bs = -FLT_MAX; int bn = 0x7fffffff;
        for (int n = tid; n < NENT; n += 256) {
            int d = drow[n];
            if (d < ds || (d == ds && n <= nc)) {
                bool used = false;
                for (int j = 0; j < r; j++) used |= (chosen[j] == n);
                if (!used) {
                    float s = srow[n];
                    if (s > bs) { bs = s; bn = n; }   // strict > keeps lowest n on tie
                }
            }
        }
        rs[tid] = bs; rn[tid] = bn;
        __syncthreads();
        for (int st = 128; st > 0; st >>= 1) {
            if (tid < st) {
                if (rs[tid+st] > rs[tid] ||
                    (rs[tid+st] == rs[tid] && rn[tid+st] < rn[tid])) {
                    rs[tid] = rs[tid+st]; rn[tid] = rn[tid+st];
                }
            }
            __syncthreads();
        }
        if (tid == 0) {
            chosen[r] = rn[0];
            out[b*KTOP + r]           = (float)rn[0];
            out[BQ*KTOP + b*KTOP + r] = rs[0];
        }
        __syncthreads();
    }
}

// ---------------------------------------------------------------------------
extern "C" void kernel_launch(void* const* d_in, const int* in_sizes, int n_in,
                              void* d_out, int out_size, void* d_ws, size_t ws_size,
                              hipStream_t stream)
{
    const int*   head = (const int*)d_in[0];
    const int*   rel  = (const int*)d_in[1];
    const float* E    = (const float*)d_in[2];
    const float* Rm   = (const float*)d_in[3];
    const float* proj = (const float*)d_in[4];
    // d_in[5] = k (always 10)

    char* ws = (char*)d_ws;
    float*         tgtT   = (float*)(ws);                    // 65536 B
    unsigned*      thash  = (unsigned*)(ws + 65536);         // 1024 B
    unsigned*      ahash  = (unsigned*)(ws + 66560);         // 1.6 MB
    float*         scores = (float*)(ws + 1666560);          // 25.6 MB
    unsigned char* dist8  = (unsigned char*)(ws + 27266560); // 6.4 MB
    int*           dsG    = (int*)(ws + 33666560);           // 256 B
    int*           ncG    = (int*)(ws + 33666816);           // 256 B
    float*         out    = (float*)d_out;

    hipLaunchKernelGGL(k_targets, dim3(BQ), dim3(128), 0, stream,
                       head, rel, E, Rm, proj, tgtT, thash);
    hipLaunchKernelGGL(k_gemm, dim3((NENT + TILE_E - 1)/TILE_E), dim3(K2_THREADS), 0, stream,
                       E, proj, tgtT, ahash, scores);
    hipLaunchKernelGGL(k_prep, dim3(BQ), dim3(256), 0, stream,
                       ahash, thash, dist8, dsG, ncG);
    hipLaunchKernelGGL(k_top, dim3(BQ), dim3(256), 0, stream,
                       dist8, scores, dsG, ncG, out);
}

// Round 3
// 1111.766 us; speedup vs baseline: 3.4263x; 3.4263x over previous
//
#include <hip/hip_runtime.h>
#include <hip/hip_bf16.h>
#include <float.h>

// Problem constants (fixed by the reference)
constexpr int NENT  = 100000;
constexpr int DDIM  = 256;
constexpr int BQ    = 64;
constexpr int CANDN = 10000;
constexpr int KTOP  = 10;
constexpr int NSLICE = 16;
constexpr int SLICE  = 6272;    // 16*6272 = 100352 >= NENT, multiple of 4

// ---------------------------------------------------------------------------
// K1: targets (stored transposed [d][b]) + query hash codes (packed 4x u32)
// ---------------------------------------------------------------------------
__global__ __launch_bounds__(128) void k_targets(
    const int* __restrict__ head, const int* __restrict__ rel,
    const float* __restrict__ E, const float* __restrict__ Rm,
    const float* __restrict__ proj,
    float* __restrict__ tgtT, unsigned* __restrict__ thash)
{
    __shared__ float tg[DDIM];
    int b = blockIdx.x;
    int tid = threadIdx.x;
    int h = head[b], r = rel[b];
    for (int d = tid; d < DDIM; d += 128) {
        float v = E[h*DDIM + d] * Rm[r*DDIM + d];
        tg[d] = v;
        tgtT[d*BQ + b] = v;   // transposed for coalesced W-staging in K2
    }
    __syncthreads();
    int t = tid >> 5, hh = tid & 31;
    float acc = 0.f;
    #pragma unroll 8
    for (int d = 0; d < DDIM; d++)
        acc += tg[d] * proj[(t*DDIM + d)*32 + hh];
    unsigned long long m = __ballot(acc > 0.0f);
    int lane = tid & 63, w = tid >> 6;
    if (lane == 0) {
        // wave0 -> words t=0,1 ; wave1 -> words t=2,3 ; bit position = h
        thash[b*4 + w*2 + 0] = (unsigned)(m & 0xffffffffull);
        thash[b*4 + w*2 + 1] = (unsigned)(m >> 32);
    }
}

// ---------------------------------------------------------------------------
// K2: fused GEMM  out[n][c] = sum_d E[n][d] * W[d][c]
//     cols 0..127  -> hash bits (proj), packed into ahash[n][4]
//     cols 128..191 -> DistMult scores vs the 64 query targets -> scores[b][n]
// ---------------------------------------------------------------------------
constexpr int TILE_E = 128;
constexpr int KB = 32;
constexpr int COLS = 192;
constexpr int K2_THREADS = 384;
constexpr int ETS = 132;   // Et row stride (padded, 16B-aligned)

__global__ __launch_bounds__(K2_THREADS) void k_gemm(
    const float* __restrict__ E, const float* __restrict__ proj,
    const float* __restrict__ tgtT,
    unsigned* __restrict__ ahash, float* __restrict__ scores)
{
    __shared__ __align__(16) float Wt[KB*COLS];      // [dd][col]   24576 B
    __shared__ __align__(16) float Et[KB*ETS];       // [dd][e]     16896 B
    __shared__ __align__(16) unsigned bitsW[TILE_E*4]; //            2048 B

    int tid = threadIdx.x;
    int cg = tid % 48;           // 4 cols: c0 = 4*cg
    int eg = tid / 48;           // 16 entities: e = 16*eg .. +15
    int n0 = blockIdx.x * TILE_E;

    float acc[16][4];
    #pragma unroll
    for (int i = 0; i < 16; i++) {
        acc[i][0] = 0.f; acc[i][1] = 0.f; acc[i][2] = 0.f; acc[i][3] = 0.f;
    }

    for (int ch = 0; ch < DDIM/KB; ch++) {
        int d0 = ch * KB;
        __syncthreads();
        // ---- stage W chunk: 32 x 192 floats ----
        #pragma unroll
        for (int s = 0; s < 4; s++) {
            int f  = tid + s*K2_THREADS;       // < 1536 float4s
            int dr = f / 48;
            int cp = (f % 48) * 4;
            float4 v;
            if (cp < 128) {
                int t = cp >> 5;
                v = *(const float4*)(proj + (t*DDIM + d0 + dr)*32 + (cp & 31));
            } else {
                v = *(const float4*)(tgtT + (d0 + dr)*BQ + (cp - 128));
            }
            *(float4*)&Wt[dr*COLS + cp] = v;
        }
        // ---- stage E chunk transposed: Et[dd][row] ----
        #pragma unroll
        for (int s = 0; s < 3; s++) {
            int f = tid + s*K2_THREADS;
            if (f < 1024) {
                int row = f >> 3;
                int cj  = (f & 7) * 4;
                int n = n0 + row; if (n >= NENT) n = NENT - 1;  // clamp (unused rows)
                float4 v = *(const float4*)(E + n*DDIM + d0 + cj);
                Et[(cj+0)*ETS + row] = v.x;
                Et[(cj+1)*ETS + row] = v.y;
                Et[(cj+2)*ETS + row] = v.z;
                Et[(cj+3)*ETS + row] = v.w;
            }
        }
        __syncthreads();
        // ---- compute: 32 d-steps, 64 FMA per step per thread ----
        #pragma unroll 4
        for (int dd = 0; dd < KB; dd++) {
            float4 w = *(const float4*)&Wt[dd*COLS + cg*4];
            const float* ep = &Et[dd*ETS + eg*16];
            float4 e0 = *(const float4*)(ep + 0);
            float4 e1 = *(const float4*)(ep + 4);
            float4 e2 = *(const float4*)(ep + 8);
            float4 e3 = *(const float4*)(ep + 12);
            float ev[16] = {e0.x,e0.y,e0.z,e0.w, e1.x,e1.y,e1.z,e1.w,
                            e2.x,e2.y,e2.z,e2.w, e3.x,e3.y,e3.z,e3.w};
            #pragma unroll
            for (int i = 0; i < 16; i++) {
                acc[i][0] += ev[i] * w.x;
                acc[i][1] += ev[i] * w.y;
                acc[i][2] += ev[i] * w.z;
                acc[i][3] += ev[i] * w.w;
            }
        }
    }

    // ---- emit ----
    __syncthreads();
    for (int i = tid; i < TILE_E*4; i += K2_THREADS) bitsW[i] = 0u;
    __syncthreads();
    if (cg < 32) {
        // hash cols: c0 = 4*cg in [0,128)
        int t  = (cg*4) >> 5;
        int sh = (cg*4) & 31;
        #pragma unroll
        for (int i = 0; i < 16; i++) {
            unsigned m = (acc[i][0] > 0.f ? 1u : 0u) | (acc[i][1] > 0.f ? 2u : 0u)
                       | (acc[i][2] > 0.f ? 4u : 0u) | (acc[i][3] > 0.f ? 8u : 0u);
            atomicOr(&bitsW[(eg*16 + i)*4 + t], m << sh);
        }
    } else {
        // score cols: b = 4*cg - 128 .. +3
        int b0 = cg*4 - 128;
        #pragma unroll
        for (int c = 0; c < 4; c++) {
            int b = b0 + c;
            #pragma unroll
            for (int j = 0; j < 4; j++) {
                int n = n0 + eg*16 + j*4;
                if (n < NENT) {
                    float4 v = make_float4(acc[j*4+0][c], acc[j*4+1][c],
                                           acc[j*4+2][c], acc[j*4+3][c]);
                    *(float4*)(scores + (size_t)b*NENT + n) = v;
                }
            }
        }
    }
    __syncthreads();
    if (tid < TILE_E) {
        int n = n0 + tid;
        if (n < NENT) {
            uint4 v = *(uint4*)&bitsW[tid*4];
            *(uint4*)(ahash + n*4) = v;
        }
    }
}

// ---------------------------------------------------------------------------
// K3: per-query dist bytes + histogram -> d*, quota R; then a single wave
// finds nCut = index of the R-th entity (index order) with dist == d*.
// Candidacy is then the pure predicate: d < d*  ||  (d == d* && n <= nCut).
// ---------------------------------------------------------------------------
__global__ __launch_bounds__(256) void k_prep(
    const unsigned* __restrict__ ahash, const unsigned* __restrict__ thash,
    unsigned char* __restrict__ dist8, int* __restrict__ dsG, int* __restrict__ ncG)
{
    __shared__ unsigned hist[129];
    __shared__ int dsS, rS;
    int b = blockIdx.x, tid = threadIdx.x;
    for (int i = tid; i < 129; i += 256) hist[i] = 0u;
    __syncthreads();
    uint4 tw = *(const uint4*)(thash + b*4);
    unsigned char* drow = dist8 + (size_t)b * NENT;
    for (int n = tid; n < NENT; n += 256) {
        uint4 a = *(const uint4*)(ahash + (size_t)n*4);
        int d = __popc(a.x^tw.x) + __popc(a.y^tw.y) +
                __popc(a.z^tw.z) + __popc(a.w^tw.w);
        drow[n] = (unsigned char)d;
        atomicAdd(&hist[d], 1u);
    }
    __syncthreads();
    if (tid == 0) {
        unsigned cum = 0;
        for (int d = 0; d < 129; d++) {
            unsigned c = cum + hist[d];
            if (c >= (unsigned)CANDN) {
                dsS = d; rS = (int)(CANDN - cum); dsG[b] = d;
                break;
            }
            cum = c;
        }
    }
    __syncthreads();
    if (tid < 64) {   // wave 0 only: find nCut (uniform loop, ballot scan)
        int ds = dsS;
        unsigned R = (unsigned)rS;   // 1 <= R <= hist[ds]
        unsigned cnt = 0;
        for (int base = 0; base < NENT; base += 64) {
            int n = base + tid;
            bool eq = (n < NENT) && (drow[n] == (unsigned char)ds);
            unsigned long long m = __ballot(eq);
            unsigned c = __popcll(m);
            if (cnt + c >= R) {
                unsigned pre = __popcll(m & ((1ull << tid) - 1ull));
                if (eq && (cnt + pre + 1u == R)) ncG[b] = n;
                break;
            }
            cnt += c;
        }
    }
}

// ---------------------------------------------------------------------------
// K4a: per-(query, slice) single-pass top-10.
// grid (NSLICE, BQ); per-thread sorted top-10 + block tournament merge.
// ---------------------------------------------------------------------------
__global__ __launch_bounds__(256) void k_part(
    const unsigned char* __restrict__ dist8, const float* __restrict__ scores,
    const int* __restrict__ dsG, const int* __restrict__ ncG,
    float* __restrict__ partS, int* __restrict__ partI)
{
    __shared__ float rs[256];
    __shared__ int   ri[256];
    __shared__ int   rt[256];

    int s = blockIdx.x, b = blockIdx.y, tid = threadIdx.x;
    int ds = dsG[b], nc = ncG[b];
    const unsigned char* drow = dist8 + (size_t)b*NENT;
    const float* srow = scores + (size_t)b*NENT;
    int n0 = s*SLICE;
    int n1 = n0 + SLICE; if (n1 > NENT) n1 = NENT;

    float topS[KTOP]; int topI[KTOP];
    #pragma unroll
    for (int i = 0; i < KTOP; i++) { topS[i] = -FLT_MAX; topI[i] = 0x7fffffff; }

    for (int n = n0 + tid*4; n < n1; n += 1024) {
        uchar4 dv = *(const uchar4*)(drow + n);
        unsigned char da[4] = {dv.x, dv.y, dv.z, dv.w};
        #pragma unroll
        for (int i = 0; i < 4; i++) {
            int d = da[i];
            int nn = n + i;
            if (d < ds || (d == ds && nn <= nc)) {
                float sc = srow[nn];
                if (sc > topS[KTOP-1]) {
                    int p = KTOP - 1;
                    while (p > 0 && topS[p-1] < sc) {
                        topS[p] = topS[p-1]; topI[p] = topI[p-1]; p--;
                    }
                    topS[p] = sc; topI[p] = nn;
                }
            }
        }
    }

    // block merge: 10 rounds of argmax over per-thread sorted lists
    int ph = 0;
    for (int r = 0; r < KTOP; r++) {
        rs[tid] = topS[ph]; ri[tid] = topI[ph]; rt[tid] = tid;
        __syncthreads();
        for (int st = 128; st > 0; st >>= 1) {
            if (tid < st) {
                bool take = (rs[tid+st] > rs[tid]) ||
                            (rs[tid+st] == rs[tid] && ri[tid+st] < ri[tid]);
                if (take) { rs[tid]=rs[tid+st]; ri[tid]=ri[tid+st]; rt[tid]=rt[tid+st]; }
            }
            __syncthreads();
        }
        if (tid == 0) {
            partS[((size_t)b*NSLICE + s)*KTOP + r] = rs[0];
            partI[((size_t)b*NSLICE + s)*KTOP + r] = ri[0];
        }
        int winner = rt[0];
        __syncthreads();
        if (tid == winner) ph++;
        __syncthreads();
    }
}

// ---------------------------------------------------------------------------
// K4b: final 16-way merge of sorted 10-lists per query.
// ---------------------------------------------------------------------------
__global__ __launch_bounds__(64) void k_merge(
    const float* __restrict__ partS, const int* __restrict__ partI,
    float* __restrict__ out)
{
    __shared__ float sc[NSLICE*KTOP];
    __shared__ int   ix[NSLICE*KTOP];
    int b = blockIdx.x, tid = threadIdx.x;
    for (int i = tid; i < NSLICE*KTOP; i += 64) {
        sc[i] = partS[(size_t)b*NSLICE*KTOP + i];
        ix[i] = partI[(size_t)b*NSLICE*KTOP + i];
    }
    __syncthreads();
    if (tid == 0) {
        int ptr[NSLICE];
        #pragma unroll
        for (int s = 0; s < NSLICE; s++) ptr[s] = 0;
        for (int r = 0; r < KTOP; r++) {
            float bs = -FLT_MAX; int bi = 0x7fffffff; int bsl = 0;
            for (int s = 0; s < NSLICE; s++) {
                if (ptr[s] < KTOP) {
                    float v  = sc[s*KTOP + ptr[s]];
                    int   id = ix[s*KTOP + ptr[s]];
                    if (v > bs || (v == bs && id < bi)) { bs = v; bi = id; bsl = s; }
                }
            }
            ptr[bsl]++;
            out[b*KTOP + r]           = (float)bi;
            out[BQ*KTOP + b*KTOP + r] = bs;
        }
    }
}

// ---------------------------------------------------------------------------
extern "C" void kernel_launch(void* const* d_in, const int* in_sizes, int n_in,
                              void* d_out, int out_size, void* d_ws, size_t ws_size,
                              hipStream_t stream)
{
    const int*   head = (const int*)d_in[0];
    const int*   rel  = (const int*)d_in[1];
    const float* E    = (const float*)d_in[2];
    const float* Rm   = (const float*)d_in[3];
    const float* proj = (const float*)d_in[4];
    // d_in[5] = k (always 10)

    char* ws = (char*)d_ws;
    float*         tgtT   = (float*)(ws);                    // 65536 B
    unsigned*      thash  = (unsigned*)(ws + 65536);         // 1024 B
    unsigned*      ahash  = (unsigned*)(ws + 66560);         // 1.6 MB
    float*         scores = (float*)(ws + 1666560);          // 25.6 MB
    unsigned char* dist8  = (unsigned char*)(ws + 27266560); // 6.4 MB
    int*           dsG    = (int*)(ws + 33666560);           // 256 B
    int*           ncG    = (int*)(ws + 33666816);           // 256 B
    float*         partS  = (float*)(ws + 33667072);         // 40960 B
    int*           partI  = (int*)(ws + 33708032);           // 40960 B
    float*         out    = (float*)d_out;

    hipLaunchKernelGGL(k_targets, dim3(BQ), dim3(128), 0, stream,
                       head, rel, E, Rm, proj, tgtT, thash);
    hipLaunchKernelGGL(k_gemm, dim3((NENT + TILE_E - 1)/TILE_E), dim3(K2_THREADS), 0, stream,
                       E, proj, tgtT, ahash, scores);
    hipLaunchKernelGGL(k_prep, dim3(BQ), dim3(256), 0, stream,
                       ahash, thash, dist8, dsG, ncG);
    hipLaunchKernelGGL(k_part, dim3(NSLICE, BQ), dim3(256), 0, stream,
                       dist8, scores, dsG, ncG, partS, partI);
    hipLaunchKernelGGL(k_merge, dim3(BQ), dim3(64), 0, stream,
                       partS, partI, out);
}

// Round 4
// 570.333 us; speedup vs baseline: 6.6790x; 1.9493x over previous
//
#include <hip/hip_runtime.h>
#include <hip/hip_bf16.h>
#include <float.h>

// Problem constants (fixed by the reference)
constexpr int NENT  = 100000;
constexpr int DDIM  = 256;
constexpr int BQ    = 64;
constexpr int CANDN = 10000;
constexpr int KTOP  = 10;
constexpr int NSLICE = 16;
constexpr int SLICE  = 6272;    // 16*6272 = 100352 >= NENT, multiple of 4
constexpr int HPAD   = 132;     // histG per-(b,s) stride

// ---------------------------------------------------------------------------
// K1: targets (stored transposed [d][b]) + query hash codes (packed 4x u32)
// ---------------------------------------------------------------------------
__global__ __launch_bounds__(128) void k_targets(
    const int* __restrict__ head, const int* __restrict__ rel,
    const float* __restrict__ E, const float* __restrict__ Rm,
    const float* __restrict__ proj,
    float* __restrict__ tgtT, unsigned* __restrict__ thash)
{
    __shared__ float tg[DDIM];
    int b = blockIdx.x;
    int tid = threadIdx.x;
    int h = head[b], r = rel[b];
    for (int d = tid; d < DDIM; d += 128) {
        float v = E[h*DDIM + d] * Rm[r*DDIM + d];
        tg[d] = v;
        tgtT[d*BQ + b] = v;   // transposed for coalesced W-staging in K2
    }
    __syncthreads();
    int t = tid >> 5, hh = tid & 31;
    float acc = 0.f;
    #pragma unroll 8
    for (int d = 0; d < DDIM; d++)
        acc += tg[d] * proj[(t*DDIM + d)*32 + hh];
    unsigned long long m = __ballot(acc > 0.0f);
    int lane = tid & 63, w = tid >> 6;
    if (lane == 0) {
        // wave0 -> words t=0,1 ; wave1 -> words t=2,3 ; bit position = h
        thash[b*4 + w*2 + 0] = (unsigned)(m & 0xffffffffull);
        thash[b*4 + w*2 + 1] = (unsigned)(m >> 32);
    }
}

// ---------------------------------------------------------------------------
// K2: fused GEMM  out[n][c] = sum_d E[n][d] * W[d][c]
//     cols 0..127  -> hash bits (proj), packed into ahash[n][4]
//     cols 128..191 -> DistMult scores vs the 64 query targets -> scores[b][n]
// ---------------------------------------------------------------------------
constexpr int TILE_E = 128;
constexpr int KB = 32;
constexpr int COLS = 192;
constexpr int K2_THREADS = 384;
constexpr int ETS = 132;   // Et row stride (padded, 16B-aligned)

__global__ __launch_bounds__(K2_THREADS) void k_gemm(
    const float* __restrict__ E, const float* __restrict__ proj,
    const float* __restrict__ tgtT,
    unsigned* __restrict__ ahash, float* __restrict__ scores)
{
    __shared__ __align__(16) float Wt[KB*COLS];      // [dd][col]   24576 B
    __shared__ __align__(16) float Et[KB*ETS];       // [dd][e]     16896 B
    __shared__ __align__(16) unsigned bitsW[TILE_E*4]; //            2048 B

    int tid = threadIdx.x;
    int cg = tid % 48;           // 4 cols: c0 = 4*cg
    int eg = tid / 48;           // 16 entities: e = 16*eg .. +15
    int n0 = blockIdx.x * TILE_E;

    float acc[16][4];
    #pragma unroll
    for (int i = 0; i < 16; i++) {
        acc[i][0] = 0.f; acc[i][1] = 0.f; acc[i][2] = 0.f; acc[i][3] = 0.f;
    }

    for (int ch = 0; ch < DDIM/KB; ch++) {
        int d0 = ch * KB;
        __syncthreads();
        // ---- stage W chunk: 32 x 192 floats ----
        #pragma unroll
        for (int s = 0; s < 4; s++) {
            int f  = tid + s*K2_THREADS;       // < 1536 float4s
            int dr = f / 48;
            int cp = (f % 48) * 4;
            float4 v;
            if (cp < 128) {
                int t = cp >> 5;
                v = *(const float4*)(proj + (t*DDIM + d0 + dr)*32 + (cp & 31));
            } else {
                v = *(const float4*)(tgtT + (d0 + dr)*BQ + (cp - 128));
            }
            *(float4*)&Wt[dr*COLS + cp] = v;
        }
        // ---- stage E chunk transposed: Et[dd][row] ----
        #pragma unroll
        for (int s = 0; s < 3; s++) {
            int f = tid + s*K2_THREADS;
            if (f < 1024) {
                int row = f >> 3;
                int cj  = (f & 7) * 4;
                int n = n0 + row; if (n >= NENT) n = NENT - 1;  // clamp (unused rows)
                float4 v = *(const float4*)(E + n*DDIM + d0 + cj);
                Et[(cj+0)*ETS + row] = v.x;
                Et[(cj+1)*ETS + row] = v.y;
                Et[(cj+2)*ETS + row] = v.z;
                Et[(cj+3)*ETS + row] = v.w;
            }
        }
        __syncthreads();
        // ---- compute: 32 d-steps, 64 FMA per step per thread ----
        #pragma unroll 4
        for (int dd = 0; dd < KB; dd++) {
            float4 w = *(const float4*)&Wt[dd*COLS + cg*4];
            const float* ep = &Et[dd*ETS + eg*16];
            float4 e0 = *(const float4*)(ep + 0);
            float4 e1 = *(const float4*)(ep + 4);
            float4 e2 = *(const float4*)(ep + 8);
            float4 e3 = *(const float4*)(ep + 12);
            float ev[16] = {e0.x,e0.y,e0.z,e0.w, e1.x,e1.y,e1.z,e1.w,
                            e2.x,e2.y,e2.z,e2.w, e3.x,e3.y,e3.z,e3.w};
            #pragma unroll
            for (int i = 0; i < 16; i++) {
                acc[i][0] += ev[i] * w.x;
                acc[i][1] += ev[i] * w.y;
                acc[i][2] += ev[i] * w.z;
                acc[i][3] += ev[i] * w.w;
            }
        }
    }

    // ---- emit ----
    __syncthreads();
    for (int i = tid; i < TILE_E*4; i += K2_THREADS) bitsW[i] = 0u;
    __syncthreads();
    if (cg < 32) {
        // hash cols: c0 = 4*cg in [0,128)
        int t  = (cg*4) >> 5;
        int sh = (cg*4) & 31;
        #pragma unroll
        for (int i = 0; i < 16; i++) {
            unsigned m = (acc[i][0] > 0.f ? 1u : 0u) | (acc[i][1] > 0.f ? 2u : 0u)
                       | (acc[i][2] > 0.f ? 4u : 0u) | (acc[i][3] > 0.f ? 8u : 0u);
            atomicOr(&bitsW[(eg*16 + i)*4 + t], m << sh);
        }
    } else {
        // score cols: b = 4*cg - 128 .. +3
        int b0 = cg*4 - 128;
        #pragma unroll
        for (int c = 0; c < 4; c++) {
            int b = b0 + c;
            #pragma unroll
            for (int j = 0; j < 4; j++) {
                int n = n0 + eg*16 + j*4;
                if (n < NENT) {
                    float4 v = make_float4(acc[j*4+0][c], acc[j*4+1][c],
                                           acc[j*4+2][c], acc[j*4+3][c]);
                    *(float4*)(scores + (size_t)b*NENT + n) = v;
                }
            }
        }
    }
    __syncthreads();
    if (tid < TILE_E) {
        int n = n0 + tid;
        if (n < NENT) {
            uint4 v = *(uint4*)&bitsW[tid*4];
            *(uint4*)(ahash + n*4) = v;
        }
    }
}

// ---------------------------------------------------------------------------
// K3a: per-(query,slice) distance bytes + slice histogram (no global atomics).
// ---------------------------------------------------------------------------
__global__ __launch_bounds__(256) void k_dist(
    const unsigned* __restrict__ ahash, const unsigned* __restrict__ thash,
    unsigned char* __restrict__ dist8, unsigned short* __restrict__ histG)
{
    __shared__ unsigned hist[HPAD];
    int s = blockIdx.x, b = blockIdx.y, tid = threadIdx.x;
    for (int i = tid; i < HPAD; i += 256) hist[i] = 0u;
    uint4 tw = *(const uint4*)(thash + b*4);
    __syncthreads();
    int n0 = s*SLICE;
    int n1 = n0 + SLICE; if (n1 > NENT) n1 = NENT;
    unsigned char* drow = dist8 + (size_t)b*NENT;
    for (int n = n0 + tid*4; n < n1; n += 1024) {
        int dv[4];
        #pragma unroll
        for (int i = 0; i < 4; i++) {
            uint4 a = *(const uint4*)(ahash + (size_t)(n+i)*4);
            dv[i] = __popc(a.x^tw.x) + __popc(a.y^tw.y) +
                    __popc(a.z^tw.z) + __popc(a.w^tw.w);
            atomicAdd(&hist[dv[i]], 1u);
        }
        uchar4 o = make_uchar4((unsigned char)dv[0], (unsigned char)dv[1],
                               (unsigned char)dv[2], (unsigned char)dv[3]);
        *(uchar4*)(drow + n) = o;
    }
    __syncthreads();
    unsigned short* hrow = histG + ((size_t)b*NSLICE + s)*HPAD;
    for (int i = tid; i < 129; i += 256) hrow[i] = (unsigned short)hist[i];
}

// ---------------------------------------------------------------------------
// K3b: per-query (single wave): total histogram -> d*, quota R; slice prefix
// locates the slice holding the R-th boundary entity; ballot-scan that slice
// only -> nCut. Candidacy predicate: d < d* || (d == d* && n <= nCut).
// ---------------------------------------------------------------------------
__global__ __launch_bounds__(64) void k_cut(
    const unsigned char* __restrict__ dist8, const unsigned short* __restrict__ histG,
    int* __restrict__ dsG, int* __restrict__ ncG)
{
    __shared__ unsigned histT[HPAD];
    __shared__ int dsS, slS, rpS;
    int b = blockIdx.x, tid = threadIdx.x;
    for (int d = tid; d < 129; d += 64) {
        unsigned sum = 0;
        for (int s = 0; s < NSLICE; s++)
            sum += histG[((size_t)b*NSLICE + s)*HPAD + d];
        histT[d] = sum;
    }
    __syncthreads();
    if (tid == 0) {
        unsigned cum = 0; int ds = 128; unsigned R = 1;
        for (int d = 0; d < 129; d++) {
            unsigned c = cum + histT[d];
            if (c >= (unsigned)CANDN) { ds = d; R = (unsigned)CANDN - cum; break; }
            cum = c;
        }
        dsS = ds; dsG[b] = ds;
        unsigned acc = 0;
        for (int s = 0; s < NSLICE; s++) {
            unsigned c = histG[((size_t)b*NSLICE + s)*HPAD + ds];
            if (acc + c >= R) { slS = s; rpS = (int)(R - acc); break; }
            acc += c;
        }
    }
    __syncthreads();
    int ds = dsS;
    unsigned Rp = (unsigned)rpS;
    const unsigned char* drow = dist8 + (size_t)b*NENT;
    int sBase = slS*SLICE;
    int sEnd = sBase + SLICE; if (sEnd > NENT) sEnd = NENT;
    unsigned cnt = 0;
    for (int base = sBase; base < sEnd; base += 64) {
        int n = base + tid;
        bool eq = (n < sEnd) && (drow[n] == (unsigned char)ds);
        unsigned long long m = __ballot(eq);
        unsigned c = __popcll(m);
        if (cnt + c >= Rp) {
            unsigned pre = __popcll(m & ((1ull << tid) - 1ull));
            if (eq && (cnt + pre + 1u == Rp)) ncG[b] = n;
            break;
        }
        cnt += c;
    }
}

// ---------------------------------------------------------------------------
// K4a: per-(query, slice) single-pass top-10.
// grid (NSLICE, BQ); per-thread sorted top-10 + block tournament merge.
// ---------------------------------------------------------------------------
__global__ __launch_bounds__(256) void k_part(
    const unsigned char* __restrict__ dist8, const float* __restrict__ scores,
    const int* __restrict__ dsG, const int* __restrict__ ncG,
    float* __restrict__ partS, int* __restrict__ partI)
{
    __shared__ float rs[256];
    __shared__ int   ri[256];
    __shared__ int   rt[256];

    int s = blockIdx.x, b = blockIdx.y, tid = threadIdx.x;
    int ds = dsG[b], nc = ncG[b];
    const unsigned char* drow = dist8 + (size_t)b*NENT;
    const float* srow = scores + (size_t)b*NENT;
    int n0 = s*SLICE;
    int n1 = n0 + SLICE; if (n1 > NENT) n1 = NENT;

    float topS[KTOP]; int topI[KTOP];
    #pragma unroll
    for (int i = 0; i < KTOP; i++) { topS[i] = -FLT_MAX; topI[i] = 0x7fffffff; }

    for (int n = n0 + tid*4; n < n1; n += 1024) {
        uchar4 dv = *(const uchar4*)(drow + n);
        unsigned char da[4] = {dv.x, dv.y, dv.z, dv.w};
        #pragma unroll
        for (int i = 0; i < 4; i++) {
            int d = da[i];
            int nn = n + i;
            if (d < ds || (d == ds && nn <= nc)) {
                float sc = srow[nn];
                if (sc > topS[KTOP-1]) {
                    int p = KTOP - 1;
                    while (p > 0 && topS[p-1] < sc) {
                        topS[p] = topS[p-1]; topI[p] = topI[p-1]; p--;
                    }
                    topS[p] = sc; topI[p] = nn;
                }
            }
        }
    }

    // block merge: 10 rounds of argmax over per-thread sorted lists
    int ph = 0;
    for (int r = 0; r < KTOP; r++) {
        rs[tid] = topS[ph]; ri[tid] = topI[ph]; rt[tid] = tid;
        __syncthreads();
        for (int st = 128; st > 0; st >>= 1) {
            if (tid < st) {
                bool take = (rs[tid+st] > rs[tid]) ||
                            (rs[tid+st] == rs[tid] && ri[tid+st] < ri[tid]);
                if (take) { rs[tid]=rs[tid+st]; ri[tid]=ri[tid+st]; rt[tid]=rt[tid+st]; }
            }
            __syncthreads();
        }
        if (tid == 0) {
            partS[((size_t)b*NSLICE + s)*KTOP + r] = rs[0];
            partI[((size_t)b*NSLICE + s)*KTOP + r] = ri[0];
        }
        int winner = rt[0];
        __syncthreads();
        if (tid == winner) ph++;
        __syncthreads();
    }
}

// ---------------------------------------------------------------------------
// K4b: final 16-way merge of sorted 10-lists per query.
// ---------------------------------------------------------------------------
__global__ __launch_bounds__(64) void k_merge(
    const float* __restrict__ partS, const int* __restrict__ partI,
    float* __restrict__ out)
{
    __shared__ float sc[NSLICE*KTOP];
    __shared__ int   ix[NSLICE*KTOP];
    int b = blockIdx.x, tid = threadIdx.x;
    for (int i = tid; i < NSLICE*KTOP; i += 64) {
        sc[i] = partS[(size_t)b*NSLICE*KTOP + i];
        ix[i] = partI[(size_t)b*NSLICE*KTOP + i];
    }
    __syncthreads();
    if (tid == 0) {
        int ptr[NSLICE];
        #pragma unroll
        for (int s = 0; s < NSLICE; s++) ptr[s] = 0;
        for (int r = 0; r < KTOP; r++) {
            float bs = -FLT_MAX; int bi = 0x7fffffff; int bsl = 0;
            for (int s = 0; s < NSLICE; s++) {
                if (ptr[s] < KTOP) {
                    float v  = sc[s*KTOP + ptr[s]];
                    int   id = ix[s*KTOP + ptr[s]];
                    if (v > bs || (v == bs && id < bi)) { bs = v; bi = id; bsl = s; }
                }
            }
            ptr[bsl]++;
            out[b*KTOP + r]           = (float)bi;
            out[BQ*KTOP + b*KTOP + r] = bs;
        }
    }
}

// ---------------------------------------------------------------------------
extern "C" void kernel_launch(void* const* d_in, const int* in_sizes, int n_in,
                              void* d_out, int out_size, void* d_ws, size_t ws_size,
                              hipStream_t stream)
{
    const int*   head = (const int*)d_in[0];
    const int*   rel  = (const int*)d_in[1];
    const float* E    = (const float*)d_in[2];
    const float* Rm   = (const float*)d_in[3];
    const float* proj = (const float*)d_in[4];
    // d_in[5] = k (always 10)

    char* ws = (char*)d_ws;
    float*          tgtT   = (float*)(ws);                    // 65536 B
    unsigned*       thash  = (unsigned*)(ws + 65536);         // 1024 B
    unsigned*       ahash  = (unsigned*)(ws + 66560);         // 1.6 MB
    float*          scores = (float*)(ws + 1666560);          // 25.6 MB
    unsigned char*  dist8  = (unsigned char*)(ws + 27266560); // 6.4 MB
    int*            dsG    = (int*)(ws + 33666560);           // 256 B
    int*            ncG    = (int*)(ws + 33666816);           // 256 B
    float*          partS  = (float*)(ws + 33667072);         // 40960 B
    int*            partI  = (int*)(ws + 33708032);           // 40960 B
    unsigned short* histG  = (unsigned short*)(ws + 33748992);// 64*16*132*2 = 270336 B
    float*          out    = (float*)d_out;

    hipLaunchKernelGGL(k_targets, dim3(BQ), dim3(128), 0, stream,
                       head, rel, E, Rm, proj, tgtT, thash);
    hipLaunchKernelGGL(k_gemm, dim3((NENT + TILE_E - 1)/TILE_E), dim3(K2_THREADS), 0, stream,
                       E, proj, tgtT, ahash, scores);
    hipLaunchKernelGGL(k_dist, dim3(NSLICE, BQ), dim3(256), 0, stream,
                       ahash, thash, dist8, histG);
    hipLaunchKernelGGL(k_cut, dim3(BQ), dim3(64), 0, stream,
                       dist8, histG, dsG, ncG);
    hipLaunchKernelGGL(k_part, dim3(NSLICE, BQ), dim3(256), 0, stream,
                       dist8, scores, dsG, ncG, partS, partI);
    hipLaunchKernelGGL(k_merge, dim3(BQ), dim3(64), 0, stream,
                       partS, partI, out);
}